// Round 6
// baseline (179.274 us; speedup 1.0000x reference)
//
#include <hip/hip_runtime.h>
#include <stdint.h>

typedef __bf16 bf16_t;
typedef __bf16 bf16x8 __attribute__((ext_vector_type(8)));
typedef __bf16 bf16x4 __attribute__((ext_vector_type(4)));
typedef float  f32x4  __attribute__((ext_vector_type(4)));

// ---------- helpers ----------

__device__ __forceinline__ void gload16(const void* g, void* lds)
{
    __builtin_amdgcn_global_load_lds(
        (__attribute__((address_space(1))) void*)(void*)g,
        (__attribute__((address_space(3))) void*)lds,
        16, 0, 0);
}

// operands swapped at call sites (mfma(b,a,acc)) -> lane holds 4 CONSECUTIVE
// COLUMNS: C[row = lane&15 (A-frag row)][col = (lane>>4)*4 + r]
__device__ __forceinline__ f32x4 mfma16(bf16x8 a, bf16x8 b, f32x4 c)
{
    return __builtin_amdgcn_mfma_f32_16x16x32_bf16(a, b, c, 0, 0, 0);
}

#define SBAR()   asm volatile("s_barrier" ::: "memory")
#define LGKM0()  asm volatile("s_waitcnt lgkmcnt(0)" ::: "memory")
#define VMCNT(N) asm volatile("s_waitcnt vmcnt(" #N ")" ::: "memory")

// ---------- prep: fused weight casts + dilated gather ----------

__global__ __launch_bounds__(256)
void prep_kernel(const float* __restrict__ Wq, const float* __restrict__ Wk,
                 const float* __restrict__ Wv, const float* __restrict__ Wo,
                 const float* __restrict__ x,
                 bf16_t* __restrict__ Wqkv, bf16_t* __restrict__ Wob,
                 bf16_t* __restrict__ Xe)
{
    const int bid = blockIdx.x;
    const int t = threadIdx.x;
    if (bid < 4096) {
        const int which = bid >> 10;
        const int blk = bid & 1023;
        const float* src = which == 0 ? Wq : which == 1 ? Wk : which == 2 ? Wv : Wo;
        bf16_t* dst = which == 3 ? Wob : Wqkv + (size_t)which * 1048576;
        const size_t i = ((size_t)blk * 256 + t) * 4;
        float4 f = *(const float4*)&src[i];
        bf16x4 o;
        o[0] = (bf16_t)f.x; o[1] = (bf16_t)f.y; o[2] = (bf16_t)f.z; o[3] = (bf16_t)f.w;
        *(bf16x4*)&dst[i] = o;
    } else {
        const int m = bid - 4096;
        const int b = m >> 11, g = (m >> 8) & 7, j = m & 255;
        const float* src = x + ((size_t)b * 4096 + g * 512 + 2 * j) * 1024;
        bf16_t* dst = Xe + (size_t)m * 1024;
        float4 f = *(const float4*)&src[t * 4];
        bf16x4 o;
        o[0] = (bf16_t)f.x; o[1] = (bf16_t)f.y; o[2] = (bf16_t)f.z; o[3] = (bf16_t)f.w;
        *(bf16x4*)&dst[t * 4] = o;
    }
}

// ---------- 256x256 8-phase GEMM: C[M,N] = A[M,K] * B[N,K]^T ----------
// 512 threads = 8 waves (2M x 4N), per-wave C = 128x64 (LDS-read:MFMA = 0.375).
// BK=64, LDS 128KB double-buffered. 4 phases per K-tile, 16 MFMA/phase,
// counted vmcnt(6) once per K-tile (never drains in main loop).
// LDS swizzle: 16B-granule bits (0,1,2) ^= (3,4,5) -- verified 0 conflicts (r3).
// XCD-chunked block swizzle (384 blocks, 48/XCD contiguous).
__global__ __launch_bounds__(512, 2)
void gemm256(const bf16_t* __restrict__ A, const bf16_t* __restrict__ B,
             bf16_t* __restrict__ C, int K, int lda, int ldb, int ldc)
{
    __shared__ __align__(16) char lds[131072];

    const int tid = threadIdx.x;
    const int w = tid >> 6, lane = tid & 63;
    const int wr = w >> 2, wc = w & 3;
    const int fr = lane & 15, fg = lane >> 4;
    const int NT = K >> 6;

    // XCD-chunked bijective swizzle over the 384-block grid
    const int lin = blockIdx.y * gridDim.x + blockIdx.x;
    const int nwg = gridDim.x * gridDim.y;
    const int cpx = nwg >> 3;
    const int L = (lin & 7) * cpx + (lin >> 3);
    const int bn = L % gridDim.x, bm = L / gridDim.x;

    // stage side: granule g fetches pre-swizzled global granule s = g ^ ((g>>3)&7)
    const int d0 = tid, d1 = 512 + tid;
    const int s0 = d0 ^ ((d0 >> 3) & 7);
    const int s1 = d1 ^ ((d1 >> 3) & 7);
    const size_t fixA0 = ((size_t)(bm * 256 + (s0 >> 9) * 128 + ((s0 >> 3) & 63)) * lda + (s0 & 7) * 8) * 2;
    const size_t fixA1 = ((size_t)(bm * 256 + (s1 >> 9) * 128 + ((s1 >> 3) & 63)) * lda + (s1 & 7) * 8) * 2;
    const size_t fixB0 = ((size_t)(bn * 256 + (s0 >> 8) * 64 + ((s0 >> 3) & 31)) * ldb + (s0 & 7) * 8) * 2;
    const size_t fixB1 = ((size_t)(bn * 256 + (s1 >> 8) * 64 + ((s1 >> 3) & 31)) * ldb + (s1 & 7) * 8) * 2;
    const size_t mqStep = (size_t)64 * lda * 2;
    const size_t nqStep = (size_t)32 * ldb * 2;
    const char* Ac = (const char*)A;
    const char* Bc = (const char*)B;
    const int ldsW = w * 1024;

#define STAGE(T, ISB, Q) do {                                                     \
    const int _b = ((T) & 1) * 65536 + (ISB) * 32768 + (Q) * 16384 + ldsW;        \
    const char *_g0, *_g1;                                                        \
    if (ISB) { _g0 = Bc + (Q)*nqStep + fixB0 + (size_t)(T)*128;                   \
               _g1 = Bc + (Q)*nqStep + fixB1 + (size_t)(T)*128; }                 \
    else     { _g0 = Ac + (Q)*mqStep + fixA0 + (size_t)(T)*128;                   \
               _g1 = Ac + (Q)*mqStep + fixA1 + (size_t)(T)*128; }                 \
    gload16(_g0, lds + _b);                                                       \
    gload16(_g1, lds + _b + 8192);                                                \
} while (0)

    // read side: swizzle = thread-constant XOR of byte bits 4-6 with fr0-2
    const int abase = wr * 8192 + fr * 128 + fg * 16;
    const int bbase = wc * 4096 + fr * 128 + fg * 16;
    const int flip  = (fr & 7) << 4;

    bf16x8 a[4][2], b0[2][2], b1[2][2];
    f32x4 acc[8][4] = {};

#define LOAD_A(MQ, CB) do {                                                                 \
    _Pragma("unroll") for (int mi = 0; mi < 4; ++mi)                                        \
    _Pragma("unroll") for (int ks = 0; ks < 2; ++ks)                                        \
        a[mi][ks] = *(const bf16x8*)(lds + (CB) + (MQ)*16384 +                              \
                                     ((abase + mi*2048 + ks*64) ^ flip));                   \
} while (0)

#define LOAD_B(REG, NQ, CB) do {                                                            \
    _Pragma("unroll") for (int ni = 0; ni < 2; ++ni)                                        \
    _Pragma("unroll") for (int ks = 0; ks < 2; ++ks)                                        \
        REG[ni][ks] = *(const bf16x8*)(lds + (CB) + 32768 + (NQ)*16384 +                    \
                                       ((bbase + ni*2048 + ks*64) ^ flip));                 \
} while (0)

#define MFMA_Q(MQ, REG, NQ) do {                                                            \
    _Pragma("unroll") for (int mi = 0; mi < 4; ++mi)                                        \
    _Pragma("unroll") for (int ni = 0; ni < 2; ++ni)                                        \
    _Pragma("unroll") for (int ks = 0; ks < 2; ++ks)                                        \
        acc[(MQ)*4+mi][(NQ)*2+ni] =                                                         \
            mfma16(REG[ni][ks], a[mi][ks], acc[(MQ)*4+mi][(NQ)*2+ni]);                      \
} while (0)

    // prologue: tile0 {A0,B0,B1,A1}, vmcnt(4); tile1 {A0,B0,B1}, vmcnt(6)
    STAGE(0, 0, 0); STAGE(0, 1, 0); STAGE(0, 1, 1); STAGE(0, 0, 1);
    VMCNT(4);
    STAGE(1, 0, 0); STAGE(1, 1, 0); STAGE(1, 1, 1);
    VMCNT(6);
    SBAR();

    for (int t = 0; t < NT - 2; ++t) {
        const int cb = (t & 1) * 65536;
        // P1: read A-q0 + B-q0, stage A1(t+1), mfma (0,0)
        LOAD_A(0, cb); LOAD_B(b0, 0, cb);
        STAGE(t + 1, 0, 1);
        SBAR(); LGKM0();
        __builtin_amdgcn_s_setprio(1); MFMA_Q(0, b0, 0); __builtin_amdgcn_s_setprio(0);
        SBAR();
        // P2: read B-q1, stage A0(t+2), mfma (0,1)
        LOAD_B(b1, 1, cb);
        STAGE(t + 2, 0, 0);
        SBAR(); LGKM0();
        __builtin_amdgcn_s_setprio(1); MFMA_Q(0, b1, 1); __builtin_amdgcn_s_setprio(0);
        SBAR();
        // P3: read A-q1, stage B0(t+2), mfma (1,1)
        LOAD_A(1, cb);
        STAGE(t + 2, 1, 0);
        SBAR(); LGKM0();
        __builtin_amdgcn_s_setprio(1); MFMA_Q(1, b1, 1); __builtin_amdgcn_s_setprio(0);
        SBAR();
        // P4: stage B1(t+2), mfma (1,0), counted vmcnt(6)
        STAGE(t + 2, 1, 1);
        SBAR();
        __builtin_amdgcn_s_setprio(1); MFMA_Q(1, b0, 0); __builtin_amdgcn_s_setprio(0);
        VMCNT(6);
        SBAR();
    }

    // tail: stage last missing half, full drain, two unstaged tiles
    STAGE(NT - 1, 0, 1);
    VMCNT(0);
    SBAR();
    for (int t = NT - 2; t < NT; ++t) {
        const int cb = (t & 1) * 65536;
        LOAD_A(0, cb); LOAD_B(b0, 0, cb);
        LGKM0();
        MFMA_Q(0, b0, 0);
        LOAD_B(b1, 1, cb);
        LGKM0();
        MFMA_Q(0, b1, 1);
        LOAD_A(1, cb);
        LGKM0();
        MFMA_Q(1, b1, 1);
        MFMA_Q(1, b0, 0);
    }

#undef STAGE
#undef LOAD_A
#undef LOAD_B
#undef MFMA_Q

    // epilogue (swapped-operand): row = ..+fr, packed cols = ..+fg*4+r
    const int r0 = bm * 256 + wr * 128 + fr;
    const int c0 = bn * 256 + wc * 64 + fg * 4;
#pragma unroll
    for (int mig = 0; mig < 8; ++mig)
#pragma unroll
        for (int nig = 0; nig < 4; ++nig) {
            bf16x4 o;
#pragma unroll
            for (int r = 0; r < 4; ++r) o[r] = (bf16_t)acc[mig][nig][r];
            *(bf16x4*)&C[(size_t)(r0 + mig * 16) * ldc + c0 + nig * 16] = o;
        }
}

// ---------- persistent 256x128 GEMM (out-projection; K=1024, NSUB sub-tiles) ----------
// grid (8,32) = 256 blocks = 1/CU, XCD-chunked. 2-phase counted vmcnt(6).
// EPI: 0 = store bf16; 2 = scatter f32 to even rows of d_out + zero odd rows.
template<int EPI, int NSUB>
__global__ __launch_bounds__(512, 2)
void gemm_mt(const bf16_t* __restrict__ A, const bf16_t* __restrict__ B,
             void* __restrict__ Cv, int lda, int ldb, int ldc)
{
    __shared__ __align__(16) char lds[98304];

    const int tid = threadIdx.x;
    const int w = tid >> 6, lane = tid & 63;
    const int wr = w >> 2, wc = w & 3;
    const int fr = lane & 15, fg = lane >> 4;

    const int lin = blockIdx.y * 8 + blockIdx.x;
    const int L = (lin & 7) * 32 + (lin >> 3);
    const int bm = L >> 3, j = L & 7;
    const int NT = NSUB * 16;

    const int s = tid ^ ((tid >> 3) & 7);
    const char* srcA  = (const char*)A + ((size_t)(bm * 256 + (s >> 3)) * lda + (s & 7) * 8) * 2;
    const char* srcB0 = (const char*)B + ((size_t)(j * NSUB * 128 + (s >> 3)) * ldb + (s & 7) * 8) * 2;
    const size_t aStep  = (size_t)64 * lda * 2;
    const size_t bStep  = (size_t)64 * ldb * 2;
    const size_t bnStep = (size_t)128 * ldb * 2;
    const int ldsW = w * 1024;

#define STG_A(T, Q) gload16(srcA + (Q) * aStep + (size_t)((T) & 15) * 128,          \
                            lds + ((T) & 1) * 49152 + (Q) * 8192 + ldsW)
#define STG_B(T, U) gload16(srcB0 + (size_t)((T) >> 4) * bnStep + (U) * bStep       \
                                  + (size_t)((T) & 15) * 128,                        \
                            lds + ((T) & 1) * 49152 + 32768 + (U) * 8192 + ldsW)

    const int flip = (fr & 7) << 4;
    const int aoff = (wr * 128 + fr) * 128 + fg * 16;
    const int boff = 32768 + (wc * 32 + fr) * 128 + fg * 16;

    bf16x8 a[4][2], b[2][2];
    f32x4 acc[8][2] = {};

#define LDA(PH, CB) do {                                                        \
    _Pragma("unroll") for (int mi = 0; mi < 4; ++mi)                            \
    _Pragma("unroll") for (int ks = 0; ks < 2; ++ks)                            \
        a[mi][ks] = *(const bf16x8*)(lds + (CB) +                               \
            ((aoff + (PH) * 8192 + mi * 2048 + ks * 64) ^ flip));               \
} while (0)

#define LDB(CB) do {                                                            \
    _Pragma("unroll") for (int ni = 0; ni < 2; ++ni)                            \
    _Pragma("unroll") for (int ks = 0; ks < 2; ++ks)                            \
        b[ni][ks] = *(const bf16x8*)(lds + (CB) +                               \
            ((boff + ni * 2048 + ks * 64) ^ flip));                             \
} while (0)

#define MF(PH) do {                                                             \
    _Pragma("unroll") for (int mi = 0; mi < 4; ++mi)                            \
    _Pragma("unroll") for (int ni = 0; ni < 2; ++ni)                            \
    _Pragma("unroll") for (int ks = 0; ks < 2; ++ks)                            \
        acc[(PH) * 4 + mi][ni] =                                                \
            mfma16(b[ni][ks], a[mi][ks], acc[(PH) * 4 + mi][ni]);               \
} while (0)

    const int r0 = bm * 256 + wr * 128 + fr;
    const int c0w = wc * 32 + fg * 4;

#define DO_EPI(SUB) do {                                                                  \
    const int _c0 = (j * NSUB + (SUB)) * 128 + c0w;                                       \
    if constexpr (EPI == 0) {                                                             \
        bf16_t* C = (bf16_t*)Cv;                                                          \
        _Pragma("unroll") for (int mig = 0; mig < 8; ++mig)                               \
        _Pragma("unroll") for (int ni = 0; ni < 2; ++ni) {                                \
            const int row = r0 + (mig >> 2) * 64 + (mig & 3) * 16;                        \
            bf16x4 o;                                                                     \
            _Pragma("unroll") for (int r = 0; r < 4; ++r) o[r] = (bf16_t)acc[mig][ni][r]; \
            *(bf16x4*)&C[(size_t)row * ldc + _c0 + ni * 16] = o;                          \
        }                                                                                 \
    } else {                                                                              \
        float* C = (float*)Cv;                                                            \
        const f32x4 z4 = {0.f, 0.f, 0.f, 0.f};                                            \
        _Pragma("unroll") for (int mig = 0; mig < 8; ++mig)                               \
        _Pragma("unroll") for (int ni = 0; ni < 2; ++ni) {                                \
            const int m  = r0 + (mig >> 2) * 64 + (mig & 3) * 16;                         \
            const int gr = ((m >> 11) << 12) | (((m >> 8) & 7) << 9) | ((m & 255) << 1);  \
            *(f32x4*)&C[(size_t)gr * 1024 + _c0 + ni * 16]       = acc[mig][ni];          \
            *(f32x4*)&C[(size_t)(gr + 1) * 1024 + _c0 + ni * 16] = z4;                    \
        }                                                                                 \
    }                                                                                     \
    _Pragma("unroll") for (int mig = 0; mig < 8; ++mig)                                   \
    _Pragma("unroll") for (int ni = 0; ni < 2; ++ni)                                      \
        acc[mig][ni] = (f32x4){0.f, 0.f, 0.f, 0.f};                                       \
} while (0)

    STG_A(0, 0); STG_A(0, 1); STG_A(0, 2); STG_A(0, 3); STG_B(0, 0); STG_B(0, 1);
    STG_A(1, 0); STG_A(1, 2); STG_B(1, 0); STG_B(1, 1);
    VMCNT(4);
    SBAR();

    for (int t = 0; t < NT - 2; ++t) {
        const int cb = (t & 1) * 49152;
        LDA(0, cb); LDB(cb);
        STG_A(t + 1, 1); STG_A(t + 1, 3);
        SBAR(); LGKM0();
        __builtin_amdgcn_s_setprio(1); MF(0); __builtin_amdgcn_s_setprio(0);
        VMCNT(6);
        SBAR();
        LDA(1, cb);
        STG_A(t + 2, 0); STG_A(t + 2, 2); STG_B(t + 2, 0); STG_B(t + 2, 1);
        SBAR(); LGKM0();
        __builtin_amdgcn_s_setprio(1); MF(1); __builtin_amdgcn_s_setprio(0);
        VMCNT(6);
        if ((t & 15) == 15) DO_EPI(t >> 4);
        SBAR();
    }

    {
        const int cb = ((NT - 2) & 1) * 49152;
        LDA(0, cb); LDB(cb);
        STG_A(NT - 1, 1); STG_A(NT - 1, 3);
        SBAR(); LGKM0();
        MF(0);
        VMCNT(6);
        SBAR();
        LDA(1, cb);
        SBAR(); LGKM0();
        MF(1);
        VMCNT(0);
        SBAR();
    }
    {
        const int cb = ((NT - 1) & 1) * 49152;
        LDA(0, cb); LDB(cb);
        LGKM0();
        MF(0);
        LDA(1, cb);
        LGKM0();
        MF(1);
    }
    DO_EPI(NSUB - 1);

#undef STG_A
#undef STG_B
#undef LDA
#undef LDB
#undef MF
#undef DO_EPI
}

// ---------- GEMM: C[M,N] = A[M,K] * B[N,K]^T (128x128 tile, swizzled m97) ----------
// flags bit0 = triangular-A K-skip (bm==0 -> K/2). Used for PV.
template<int EPI>   // 0 = store bf16, 1 = store f32
__global__ __launch_bounds__(256)
void gemm_nt(const bf16_t* __restrict__ A, const bf16_t* __restrict__ B,
             void* __restrict__ Cv,
             int K, int lda, int ldb, int ldc,
             long sA, long sB, long sC, int flags)
{
    __shared__ __align__(16) bf16_t Asm[128 * 32];
    __shared__ __align__(16) bf16_t Bsm[128 * 32];

    const int bn = blockIdx.x, bm = blockIdx.y, bz = blockIdx.z;
    const int tid  = threadIdx.x;
    const int wave = tid >> 6;
    const int lane = tid & 63;
    const int wr = wave >> 1, wc = wave & 1;

    const bf16_t* Ab = A + (long)bz * sA;
    const bf16_t* Bb = B + (long)bz * sB;

    const int Keff = ((flags & 1) && bm == 0) ? (K >> 1) : K;

    const int sw0 = tid ^ ((tid >> 3) & 3);
    const int dd1 = tid + 256;
    const int sw1 = dd1 ^ ((dd1 >> 3) & 3);
    const bf16_t* a0 = Ab + (size_t)(bm * 128 + (sw0 >> 2)) * lda + (sw0 & 3) * 8;
    const bf16_t* a1 = Ab + (size_t)(bm * 128 + (sw1 >> 2)) * lda + (sw1 & 3) * 8;
    const bf16_t* b0 = Bb + (size_t)(bn * 128 + (sw0 >> 2)) * ldb + (sw0 & 3) * 8;
    const bf16_t* b1 = Bb + (size_t)(bn * 128 + (sw1 >> 2)) * ldb + (sw1 & 3) * 8;
    char* ldsA = (char*)Asm + wave * 1024;
    char* ldsB = (char*)Bsm + wave * 1024;

    f32x4 acc[4][4] = {};

    const int frow = lane & 15;
    const int fk   = (lane >> 4) * 8;
    const int flip = (frow & 6) << 2;

    for (int k0 = 0; k0 < Keff; k0 += 32) {
        gload16(a0, ldsA);
        gload16(a1, ldsA + 4096);
        gload16(b0, ldsB);
        gload16(b1, ldsB + 4096);
        a0 += 32; a1 += 32; b0 += 32; b1 += 32;
        __syncthreads();

        bf16x8 af[4], bfr[4];
#pragma unroll
        for (int mi = 0; mi < 4; ++mi)
            af[mi] = *(const bf16x8*)&Asm[(size_t)(((wr * 64 + mi * 16 + frow) * 32 + fk) ^ flip)];
#pragma unroll
        for (int ni = 0; ni < 4; ++ni)
            bfr[ni] = *(const bf16x8*)&Bsm[(size_t)(((wc * 64 + ni * 16 + frow) * 32 + fk) ^ flip)];
#pragma unroll
        for (int mi = 0; mi < 4; ++mi)
#pragma unroll
            for (int ni = 0; ni < 4; ++ni)
                acc[mi][ni] = mfma16(bfr[ni], af[mi], acc[mi][ni]);   // swapped
        __syncthreads();
    }

    const int row0 = bm * 128 + wr * 64 + frow;
    const int col0 = bn * 128 + wc * 64 + (lane >> 4) * 4;

    if constexpr (EPI == 0) {
        bf16_t* C = (bf16_t*)Cv + (long)bz * sC;
#pragma unroll
        for (int mi = 0; mi < 4; ++mi)
#pragma unroll
            for (int ni = 0; ni < 4; ++ni) {
                bf16x4 o;
#pragma unroll
                for (int r = 0; r < 4; ++r) o[r] = (bf16_t)acc[mi][ni][r];
                *(bf16x4*)&C[(size_t)(row0 + mi * 16) * ldc + col0 + ni * 16] = o;
            }
    } else {
        float* C = (float*)Cv + (long)bz * sC;
#pragma unroll
        for (int mi = 0; mi < 4; ++mi)
#pragma unroll
            for (int ni = 0; ni < 4; ++ni)
                *(f32x4*)&C[(size_t)(row0 + mi * 16) * ldc + col0 + ni * 16] = acc[mi][ni];
    }
}

// ---------- merged: QK^T GEMM (blocks 0..95) + V transpose 64x64 (rest) ----------
__global__ __launch_bounds__(256)
void qk_tr_kernel(const bf16_t* __restrict__ qkv, float* __restrict__ Smat,
                  bf16_t* __restrict__ Vt)
{
    __shared__ __align__(16) char smem[16384];
    const int bid = blockIdx.x;
    const int tid = threadIdx.x;

    if (bid < 96) {
        const int seg = bid / 3, r = bid % 3;
        const int bm = (r + 1) >> 1, bn = r >> 1;
        const bf16_t* Ab = qkv + (size_t)seg * 256 * 3072;          // Q
        const bf16_t* Bb = Ab + 1024;                                // K
        bf16_t* Asm = (bf16_t*)smem;
        bf16_t* Bsm = Asm + 4096;

        const int wave = tid >> 6, lane = tid & 63;
        const int wr = wave >> 1, wc = wave & 1;
        const int sw0 = tid ^ ((tid >> 3) & 3);
        const int dd1 = tid + 256;
        const int sw1 = dd1 ^ ((dd1 >> 3) & 3);
        const bf16_t* a0 = Ab + (size_t)(bm * 128 + (sw0 >> 2)) * 3072 + (sw0 & 3) * 8;
        const bf16_t* a1 = Ab + (size_t)(bm * 128 + (sw1 >> 2)) * 3072 + (sw1 & 3) * 8;
        const bf16_t* b0 = Bb + (size_t)(bn * 128 + (sw0 >> 2)) * 3072 + (sw0 & 3) * 8;
        const bf16_t* b1 = Bb + (size_t)(bn * 128 + (sw1 >> 2)) * 3072 + (sw1 & 3) * 8;
        char* ldsA = (char*)Asm + wave * 1024;
        char* ldsB = (char*)Bsm + wave * 1024;

        f32x4 acc[4][4] = {};
        const int frow = lane & 15;
        const int fk   = (lane >> 4) * 8;
        const int flip = (frow & 6) << 2;

        for (int k0 = 0; k0 < 1024; k0 += 32) {
            gload16(a0, ldsA);
            gload16(a1, ldsA + 4096);
            gload16(b0, ldsB);
            gload16(b1, ldsB + 4096);
            a0 += 32; a1 += 32; b0 += 32; b1 += 32;
            __syncthreads();

            bf16x8 af[4], bfr[4];
#pragma unroll
            for (int mi = 0; mi < 4; ++mi)
                af[mi] = *(const bf16x8*)&Asm[(size_t)(((wr * 64 + mi * 16 + frow) * 32 + fk) ^ flip)];
#pragma unroll
            for (int ni = 0; ni < 4; ++ni)
                bfr[ni] = *(const bf16x8*)&Bsm[(size_t)(((wc * 64 + ni * 16 + frow) * 32 + fk) ^ flip)];
#pragma unroll
            for (int mi = 0; mi < 4; ++mi)
#pragma unroll
                for (int ni = 0; ni < 4; ++ni)
                    acc[mi][ni] = mfma16(bfr[ni], af[mi], acc[mi][ni]);
            __syncthreads();
        }

        float* C = Smat + (size_t)seg * 65536;
        const int row0 = bm * 128 + wr * 64 + frow;
        const int col0 = bn * 128 + wc * 64 + (lane >> 4) * 4;
#pragma unroll
        for (int mi = 0; mi < 4; ++mi)
#pragma unroll
            for (int ni = 0; ni < 4; ++ni)
                *(f32x4*)&C[(size_t)(row0 + mi * 16) * 256 + col0 + ni * 16] = acc[mi][ni];
    } else {
        const int id2 = bid - 96;
        const int seg = id2 >> 6;
        const int rem = id2 & 63;
        const int eb = rem >> 2, kb = rem & 3;
        bf16_t* tile = (bf16_t*)smem;   // [64][65]

        const int rr = tid >> 2, cs = (tid & 3) * 16;
        const bf16_t* src = qkv + ((size_t)(seg * 256 + kb * 64 + rr)) * 3072
                                + 2048 + eb * 64 + cs;
        bf16x8 v0 = *(const bf16x8*)&src[0];
        bf16x8 v1 = *(const bf16x8*)&src[8];
#pragma unroll
        for (int i = 0; i < 8; ++i) {
            tile[rr * 65 + cs + i]     = v0[i];
            tile[rr * 65 + cs + 8 + i] = v1[i];
        }
        __syncthreads();
        bf16x8 o0, o1;
#pragma unroll
        for (int i = 0; i < 8; ++i) {
            o0[i] = tile[(cs + i) * 65 + rr];
            o1[i] = tile[(cs + 8 + i) * 65 + rr];
        }
        bf16_t* dst = Vt + (size_t)seg * 262144 + (size_t)(eb * 64 + rr) * 256 + kb * 64 + cs;
        *(bf16x8*)&dst[0] = o0;
        *(bf16x8*)&dst[8] = o1;
    }
}

// ---------- LayerNorm (in place, bf16x8, 2 rows per block) ----------
__global__ __launch_bounds__(256)
void ln_kernel(bf16_t* __restrict__ qkv,
               const float* __restrict__ gamma, const float* __restrict__ beta)
{
    const int t = threadIdx.x;
    const int r = t >> 7;
    const int row = blockIdx.x * 2 + r;
    const int which = blockIdx.y;
    bf16_t* p = qkv + (size_t)row * 3072 + which * 1024;
    const int li = t & 127;
    const int c0 = li * 8;

    bf16x8 v = *(const bf16x8*)&p[c0];
    float f[8];
    float s = 0.f, ss = 0.f;
#pragma unroll
    for (int i = 0; i < 8; ++i) { f[i] = (float)v[i]; s += f[i]; ss += f[i] * f[i]; }
#pragma unroll
    for (int o = 32; o; o >>= 1) { s += __shfl_xor(s, o); ss += __shfl_xor(ss, o); }

    __shared__ float rs_[4], rss_[4];
    const int wave = t >> 6, lane = t & 63;
    if (lane == 0) { rs_[wave] = s; rss_[wave] = ss; }
    __syncthreads();
    s  = rs_[2 * r] + rs_[2 * r + 1];
    ss = rss_[2 * r] + rss_[2 * r + 1];

    const float mu   = s * (1.f / 1024.f);
    const float var  = ss * (1.f / 1024.f) - mu * mu;
    const float rstd = rsqrtf(var + 1e-5f);

    bf16x8 o;
#pragma unroll
    for (int i = 0; i < 8; ++i)
        o[i] = (bf16_t)((f[i] - mu) * rstd * gamma[c0 + i] + beta[c0 + i]);
    *(bf16x8*)&p[c0] = o;
}

// ---------- causal softmax: S[32*256][256] f32 -> P bf16 ----------
__global__ __launch_bounds__(256)
void softmax_kernel(const float* __restrict__ S, bf16_t* __restrict__ P)
{
    const int q = blockIdx.x & 255;
    const size_t base = (size_t)blockIdx.x * 256;
    const int c = threadIdx.x;
    const bool ok = (c <= q);

    float v = ok ? S[base + c] * (1.f / 32.f) : -3.0e38f;
    float m = v;
#pragma unroll
    for (int o = 32; o; o >>= 1) m = fmaxf(m, __shfl_xor(m, o));

    __shared__ float rm[4], rsum[4];
    const int wave = c >> 6, lane = c & 63;
    if (lane == 0) rm[wave] = m;
    __syncthreads();
    m = fmaxf(fmaxf(rm[0], rm[1]), fmaxf(rm[2], rm[3]));

    float e = ok ? __expf(v - m) : 0.f;
    float s = e;
#pragma unroll
    for (int o = 32; o; o >>= 1) s += __shfl_xor(s, o);
    if (lane == 0) rsum[wave] = s;
    __syncthreads();
    s = rsum[0] + rsum[1] + rsum[2] + rsum[3];

    P[base + c] = (bf16_t)(e / s);
}

// ---------- launch ----------

extern "C" void kernel_launch(void* const* d_in, const int* in_sizes, int n_in,
                              void* d_out, int out_size, void* d_ws, size_t ws_size,
                              hipStream_t stream)
{
    const float* x     = (const float*)d_in[0];
    const float* Wq    = (const float*)d_in[1];
    const float* Wk    = (const float*)d_in[2];
    const float* Wv    = (const float*)d_in[3];
    const float* Wo    = (const float*)d_in[4];
    const float* gamma = (const float*)d_in[5];
    const float* beta  = (const float*)d_in[6];
    float* out = (float*)d_out;

    char* ws = (char*)d_ws;
    bf16_t* Xe   = (bf16_t*)(ws);                  // 8192x1024 bf16   (16 MB)
    bf16_t* Wqkv = (bf16_t*)(ws + (16u  << 20));   // 3072x1024 bf16   ( 6 MB)
    bf16_t* Wob  = (bf16_t*)(ws + (22u  << 20));   // 1024x1024 bf16   ( 2 MB)
    bf16_t* QKV  = (bf16_t*)(ws + (24u  << 20));   // 8192x3072 bf16   (48 MB)
    float*  Smat = (float*) (ws + (72u  << 20));   // 32x256x256 f32   ( 8 MB)
    bf16_t* P    = (bf16_t*)(ws + (80u  << 20));   // 32x256x256 bf16  ( 4 MB)
    bf16_t* Vt   = (bf16_t*)(ws + (84u  << 20));   // 32x1024x256 bf16 (16 MB)
    bf16_t* Y    = (bf16_t*)(ws + (100u << 20));   // 8192x1024 bf16   (16 MB)

    // prep: weight casts + dilated gather (one launch)
    prep_kernel<<<12288, 256, 0, stream>>>(Wq, Wk, Wv, Wo, x, Wqkv, Wob, Xe);

    // QKV projection: [8192,1024] x [3072,1024]^T -> [8192,3072] bf16
    // 256^2 8-phase, conflict-free swizzle, XCD-chunked (384 blocks)
    gemm256<<<dim3(12, 32), 512, 0, stream>>>(Xe, Wqkv, QKV, 1024, 1024, 1024, 3072);

    // LayerNorm q,k,v in place
    ln_kernel<<<dim3(4096, 3), 256, 0, stream>>>(QKV, gamma, beta);

    // merged: S = Q K^T (causal-skip) + V transpose
    qk_tr_kernel<<<96 + 2048, 256, 0, stream>>>(QKV, Smat, Vt);

    // causal softmax -> P bf16
    softmax_kernel<<<8192, 256, 0, stream>>>(Smat, P);

    // Y = P V per segment (tri: bm==0 blocks only need K=128)
    gemm_nt<0><<<dim3(8, 2, 32), 256, 0, stream>>>(
        P, Vt, Y, 256, 256, 256, 1024,
        65536L, 262144L, 262144L, 1);

    // out = Y Wo^T scattered to even rows of d_out, odd rows zeroed
    gemm_mt<2, 1><<<dim3(8, 32), 512, 0, stream>>>(
        Y, Wob, out, 1024, 1024, 1024);
}

// Round 7
// 171.867 us; speedup vs baseline: 1.0431x; 1.0431x over previous
//
#include <hip/hip_runtime.h>
#include <stdint.h>

typedef __bf16 bf16_t;
typedef __bf16 bf16x8 __attribute__((ext_vector_type(8)));
typedef __bf16 bf16x4 __attribute__((ext_vector_type(4)));
typedef float  f32x4  __attribute__((ext_vector_type(4)));

// ---------- helpers ----------

__device__ __forceinline__ void gload16(const void* g, void* lds)
{
    __builtin_amdgcn_global_load_lds(
        (__attribute__((address_space(1))) void*)(void*)g,
        (__attribute__((address_space(3))) void*)lds,
        16, 0, 0);
}

// operands swapped at call sites (mfma(b,a,acc)) -> lane holds 4 CONSECUTIVE
// COLUMNS: C[row = lane&15 (A-frag row)][col = (lane>>4)*4 + r]
__device__ __forceinline__ f32x4 mfma16(bf16x8 a, bf16x8 b, f32x4 c)
{
    return __builtin_amdgcn_mfma_f32_16x16x32_bf16(a, b, c, 0, 0, 0);
}

#define SBAR()   asm volatile("s_barrier" ::: "memory")
#define LGKM0()  asm volatile("s_waitcnt lgkmcnt(0)" ::: "memory")
#define VMCNT(N) asm volatile("s_waitcnt vmcnt(" #N ")" ::: "memory")

// ---------- prep: fused weight casts + dilated gather ----------

__global__ __launch_bounds__(256)
void prep_kernel(const float* __restrict__ Wq, const float* __restrict__ Wk,
                 const float* __restrict__ Wv, const float* __restrict__ Wo,
                 const float* __restrict__ x,
                 bf16_t* __restrict__ Wqkv, bf16_t* __restrict__ Wob,
                 bf16_t* __restrict__ Xe)
{
    const int bid = blockIdx.x;
    const int t = threadIdx.x;
    if (bid < 4096) {
        const int which = bid >> 10;
        const int blk = bid & 1023;
        const float* src = which == 0 ? Wq : which == 1 ? Wk : which == 2 ? Wv : Wo;
        bf16_t* dst = which == 3 ? Wob : Wqkv + (size_t)which * 1048576;
        const size_t i = ((size_t)blk * 256 + t) * 4;
        float4 f = *(const float4*)&src[i];
        bf16x4 o;
        o[0] = (bf16_t)f.x; o[1] = (bf16_t)f.y; o[2] = (bf16_t)f.z; o[3] = (bf16_t)f.w;
        *(bf16x4*)&dst[i] = o;
    } else {
        const int m = bid - 4096;
        const int b = m >> 11, g = (m >> 8) & 7, j = m & 255;
        const float* src = x + ((size_t)b * 4096 + g * 512 + 2 * j) * 1024;
        bf16_t* dst = Xe + (size_t)m * 1024;
        float4 f = *(const float4*)&src[t * 4];
        bf16x4 o;
        o[0] = (bf16_t)f.x; o[1] = (bf16_t)f.y; o[2] = (bf16_t)f.z; o[3] = (bf16_t)f.w;
        *(bf16x4*)&dst[t * 4] = o;
    }
}

// ---------- persistent 256x128 GEMM (K=1024 fixed, NSUB sub-tiles) ----------
// grid (8,32) = 256 blocks = 1/CU, XCD-chunked. 2-phase counted vmcnt(6).
// EPI: 0 = store bf16; 2 = scatter f32 to even rows of d_out + zero odd rows.
template<int EPI, int NSUB>
__global__ __launch_bounds__(512, 2)
void gemm_mt(const bf16_t* __restrict__ A, const bf16_t* __restrict__ B,
             void* __restrict__ Cv, int lda, int ldb, int ldc)
{
    __shared__ __align__(16) char lds[98304];

    const int tid = threadIdx.x;
    const int w = tid >> 6, lane = tid & 63;
    const int wr = w >> 2, wc = w & 3;
    const int fr = lane & 15, fg = lane >> 4;

    const int lin = blockIdx.y * 8 + blockIdx.x;
    const int L = (lin & 7) * 32 + (lin >> 3);
    const int bm = L >> 3, j = L & 7;
    const int NT = NSUB * 16;

    const int s = tid ^ ((tid >> 3) & 7);
    const char* srcA  = (const char*)A + ((size_t)(bm * 256 + (s >> 3)) * lda + (s & 7) * 8) * 2;
    const char* srcB0 = (const char*)B + ((size_t)(j * NSUB * 128 + (s >> 3)) * ldb + (s & 7) * 8) * 2;
    const size_t aStep  = (size_t)64 * lda * 2;
    const size_t bStep  = (size_t)64 * ldb * 2;
    const size_t bnStep = (size_t)128 * ldb * 2;
    const int ldsW = w * 1024;

#define STG_A(T, Q) gload16(srcA + (Q) * aStep + (size_t)((T) & 15) * 128,          \
                            lds + ((T) & 1) * 49152 + (Q) * 8192 + ldsW)
#define STG_B(T, U) gload16(srcB0 + (size_t)((T) >> 4) * bnStep + (U) * bStep       \
                                  + (size_t)((T) & 15) * 128,                        \
                            lds + ((T) & 1) * 49152 + 32768 + (U) * 8192 + ldsW)

    const int flip = (fr & 7) << 4;
    const int aoff = (wr * 128 + fr) * 128 + fg * 16;
    const int boff = 32768 + (wc * 32 + fr) * 128 + fg * 16;

    bf16x8 a[4][2], b[2][2];
    f32x4 acc[8][2] = {};

#define LDA(PH, CB) do {                                                        \
    _Pragma("unroll") for (int mi = 0; mi < 4; ++mi)                            \
    _Pragma("unroll") for (int ks = 0; ks < 2; ++ks)                            \
        a[mi][ks] = *(const bf16x8*)(lds + (CB) +                               \
            ((aoff + (PH) * 8192 + mi * 2048 + ks * 64) ^ flip));               \
} while (0)

#define LDB(CB) do {                                                            \
    _Pragma("unroll") for (int ni = 0; ni < 2; ++ni)                            \
    _Pragma("unroll") for (int ks = 0; ks < 2; ++ks)                            \
        b[ni][ks] = *(const bf16x8*)(lds + (CB) +                               \
            ((boff + ni * 2048 + ks * 64) ^ flip));                             \
} while (0)

#define MF(PH) do {                                                             \
    _Pragma("unroll") for (int mi = 0; mi < 4; ++mi)                            \
    _Pragma("unroll") for (int ni = 0; ni < 2; ++ni)                            \
    _Pragma("unroll") for (int ks = 0; ks < 2; ++ks)                            \
        acc[(PH) * 4 + mi][ni] =                                                \
            mfma16(b[ni][ks], a[mi][ks], acc[(PH) * 4 + mi][ni]);               \
} while (0)

    const int r0 = bm * 256 + wr * 128 + fr;
    const int c0w = wc * 32 + fg * 4;

#define DO_EPI(SUB) do {                                                                  \
    const int _c0 = (j * NSUB + (SUB)) * 128 + c0w;                                       \
    if constexpr (EPI == 0) {                                                             \
        bf16_t* C = (bf16_t*)Cv;                                                          \
        _Pragma("unroll") for (int mig = 0; mig < 8; ++mig)                               \
        _Pragma("unroll") for (int ni = 0; ni < 2; ++ni) {                                \
            const int row = r0 + (mig >> 2) * 64 + (mig & 3) * 16;                        \
            bf16x4 o;                                                                     \
            _Pragma("unroll") for (int r = 0; r < 4; ++r) o[r] = (bf16_t)acc[mig][ni][r]; \
            *(bf16x4*)&C[(size_t)row * ldc + _c0 + ni * 16] = o;                          \
        }                                                                                 \
    } else {                                                                              \
        float* C = (float*)Cv;                                                            \
        const f32x4 z4 = {0.f, 0.f, 0.f, 0.f};                                            \
        _Pragma("unroll") for (int mig = 0; mig < 8; ++mig)                               \
        _Pragma("unroll") for (int ni = 0; ni < 2; ++ni) {                                \
            const int m  = r0 + (mig >> 2) * 64 + (mig & 3) * 16;                         \
            const int gr = ((m >> 11) << 12) | (((m >> 8) & 7) << 9) | ((m & 255) << 1);  \
            *(f32x4*)&C[(size_t)gr * 1024 + _c0 + ni * 16]       = acc[mig][ni];          \
            *(f32x4*)&C[(size_t)(gr + 1) * 1024 + _c0 + ni * 16] = z4;                    \
        }                                                                                 \
    }                                                                                     \
    _Pragma("unroll") for (int mig = 0; mig < 8; ++mig)                                   \
    _Pragma("unroll") for (int ni = 0; ni < 2; ++ni)                                      \
        acc[mig][ni] = (f32x4){0.f, 0.f, 0.f, 0.f};                                       \
} while (0)

    STG_A(0, 0); STG_A(0, 1); STG_A(0, 2); STG_A(0, 3); STG_B(0, 0); STG_B(0, 1);
    STG_A(1, 0); STG_A(1, 2); STG_B(1, 0); STG_B(1, 1);
    VMCNT(4);
    SBAR();

    for (int t = 0; t < NT - 2; ++t) {
        const int cb = (t & 1) * 49152;
        LDA(0, cb); LDB(cb);
        STG_A(t + 1, 1); STG_A(t + 1, 3);
        SBAR(); LGKM0();
        __builtin_amdgcn_s_setprio(1); MF(0); __builtin_amdgcn_s_setprio(0);
        VMCNT(6);
        SBAR();
        LDA(1, cb);
        STG_A(t + 2, 0); STG_A(t + 2, 2); STG_B(t + 2, 0); STG_B(t + 2, 1);
        SBAR(); LGKM0();
        __builtin_amdgcn_s_setprio(1); MF(1); __builtin_amdgcn_s_setprio(0);
        VMCNT(6);
        if ((t & 15) == 15) DO_EPI(t >> 4);
        SBAR();
    }

    {
        const int cb = ((NT - 2) & 1) * 49152;
        LDA(0, cb); LDB(cb);
        STG_A(NT - 1, 1); STG_A(NT - 1, 3);
        SBAR(); LGKM0();
        MF(0);
        VMCNT(6);
        SBAR();
        LDA(1, cb);
        SBAR(); LGKM0();
        MF(1);
        VMCNT(0);
        SBAR();
    }
    {
        const int cb = ((NT - 1) & 1) * 49152;
        LDA(0, cb); LDB(cb);
        LGKM0();
        MF(0);
        LDA(1, cb);
        LGKM0();
        MF(1);
    }
    DO_EPI(NSUB - 1);

#undef STG_A
#undef STG_B
#undef LDA
#undef LDB
#undef MF
#undef DO_EPI
}

// ---------- GEMM: C[M,N] = A[M,K] * B[N,K]^T (128x128 tile, swizzled m97) ----------
// flags bit0 = triangular-A K-skip (bm==0 -> K/2). Used for PV.
template<int EPI>   // 0 = store bf16, 1 = store f32
__global__ __launch_bounds__(256)
void gemm_nt(const bf16_t* __restrict__ A, const bf16_t* __restrict__ B,
             void* __restrict__ Cv,
             int K, int lda, int ldb, int ldc,
             long sA, long sB, long sC, int flags)
{
    __shared__ __align__(16) bf16_t Asm[128 * 32];
    __shared__ __align__(16) bf16_t Bsm[128 * 32];

    const int bn = blockIdx.x, bm = blockIdx.y, bz = blockIdx.z;
    const int tid  = threadIdx.x;
    const int wave = tid >> 6;
    const int lane = tid & 63;
    const int wr = wave >> 1, wc = wave & 1;

    const bf16_t* Ab = A + (long)bz * sA;
    const bf16_t* Bb = B + (long)bz * sB;

    const int Keff = ((flags & 1) && bm == 0) ? (K >> 1) : K;

    const int sw0 = tid ^ ((tid >> 3) & 3);
    const int dd1 = tid + 256;
    const int sw1 = dd1 ^ ((dd1 >> 3) & 3);
    const bf16_t* a0 = Ab + (size_t)(bm * 128 + (sw0 >> 2)) * lda + (sw0 & 3) * 8;
    const bf16_t* a1 = Ab + (size_t)(bm * 128 + (sw1 >> 2)) * lda + (sw1 & 3) * 8;
    const bf16_t* b0 = Bb + (size_t)(bn * 128 + (sw0 >> 2)) * ldb + (sw0 & 3) * 8;
    const bf16_t* b1 = Bb + (size_t)(bn * 128 + (sw1 >> 2)) * ldb + (sw1 & 3) * 8;
    char* ldsA = (char*)Asm + wave * 1024;
    char* ldsB = (char*)Bsm + wave * 1024;

    f32x4 acc[4][4] = {};

    const int frow = lane & 15;
    const int fk   = (lane >> 4) * 8;
    const int flip = (frow & 6) << 2;

    for (int k0 = 0; k0 < Keff; k0 += 32) {
        gload16(a0, ldsA);
        gload16(a1, ldsA + 4096);
        gload16(b0, ldsB);
        gload16(b1, ldsB + 4096);
        a0 += 32; a1 += 32; b0 += 32; b1 += 32;
        __syncthreads();

        bf16x8 af[4], bfr[4];
#pragma unroll
        for (int mi = 0; mi < 4; ++mi)
            af[mi] = *(const bf16x8*)&Asm[(size_t)(((wr * 64 + mi * 16 + frow) * 32 + fk) ^ flip)];
#pragma unroll
        for (int ni = 0; ni < 4; ++ni)
            bfr[ni] = *(const bf16x8*)&Bsm[(size_t)(((wc * 64 + ni * 16 + frow) * 32 + fk) ^ flip)];
#pragma unroll
        for (int mi = 0; mi < 4; ++mi)
#pragma unroll
            for (int ni = 0; ni < 4; ++ni)
                acc[mi][ni] = mfma16(bfr[ni], af[mi], acc[mi][ni]);   // swapped
        __syncthreads();
    }

    const int row0 = bm * 128 + wr * 64 + frow;
    const int col0 = bn * 128 + wc * 64 + (lane >> 4) * 4;

    if constexpr (EPI == 0) {
        bf16_t* C = (bf16_t*)Cv + (long)bz * sC;
#pragma unroll
        for (int mi = 0; mi < 4; ++mi)
#pragma unroll
            for (int ni = 0; ni < 4; ++ni) {
                bf16x4 o;
#pragma unroll
                for (int r = 0; r < 4; ++r) o[r] = (bf16_t)acc[mi][ni][r];
                *(bf16x4*)&C[(size_t)(row0 + mi * 16) * ldc + col0 + ni * 16] = o;
            }
    } else {
        float* C = (float*)Cv + (long)bz * sC;
#pragma unroll
        for (int mi = 0; mi < 4; ++mi)
#pragma unroll
            for (int ni = 0; ni < 4; ++ni)
                *(f32x4*)&C[(size_t)(row0 + mi * 16) * ldc + col0 + ni * 16] = acc[mi][ni];
    }
}

// ---------- fused QK^T + causal softmax (device body) ----------
// 512 thr / 8 waves (2 wr x 4 wc). A = 128 Q-rows; B = NI*64... N = NI*16*4 cols? No:
// per-wave N_w = NI*16; block N = 4*N_w (wc strips). NI=4 -> N=256 (qb1); NI=2 -> N=128 (qb0).
// Softmax over the block's full row-band in epilogue, writes P bf16 directly.
template<int NI>
__device__ __forceinline__ void qk_block(
    const bf16_t* __restrict__ Ab, const bf16_t* __restrict__ Bb,
    bf16_t* __restrict__ Pseg, int qb, char* smem, int tid)
{
    bf16_t* Asm = (bf16_t*)smem;                 // [128][32]
    bf16_t* Bsm = (bf16_t*)(smem + 8192);        // [NI*64][32]
    float*  red = (float*)(smem + 24576);        // [128][4]

    const int w = tid >> 6, lane = tid & 63;
    const int wr = w >> 2, wc = w & 3;
    const int frow = lane & 15, fg = lane >> 4;

    const int g0 = tid, g1 = tid + 512;
    const int s0 = g0 ^ ((g0 >> 3) & 3);
    const int s1 = g1 ^ ((g1 >> 3) & 3);
    const bf16_t* a0 = Ab + (size_t)(s0 >> 2) * 3072 + (s0 & 3) * 8;
    const bf16_t* b0 = Bb + (size_t)(s0 >> 2) * 3072 + (s0 & 3) * 8;
    const bf16_t* b1 = Bb + (size_t)(s1 >> 2) * 3072 + (s1 & 3) * 8;
    char* ldsA = smem + w * 1024;
    char* ldsB = smem + 8192 + w * 1024;

    f32x4 acc[4][NI] = {};
    const int fk = fg * 8;
    const int flip = (frow & 6) << 2;
    const int Nw = NI * 16;

    for (int k0 = 0; k0 < 1024; k0 += 32) {
        gload16(a0, ldsA);
        gload16(b0, ldsB);
        if (NI == 4) gload16(b1, ldsB + 8192);
        a0 += 32; b0 += 32; b1 += 32;
        __syncthreads();

        bf16x8 af[4], bf_[NI];
#pragma unroll
        for (int mi = 0; mi < 4; ++mi)
            af[mi] = *(const bf16x8*)&Asm[((wr * 64 + mi * 16 + frow) * 32 + fk) ^ flip];
#pragma unroll
        for (int ni = 0; ni < NI; ++ni)
            bf_[ni] = *(const bf16x8*)&Bsm[((wc * Nw + ni * 16 + frow) * 32 + fk) ^ flip];
#pragma unroll
        for (int mi = 0; mi < 4; ++mi)
#pragma unroll
            for (int ni = 0; ni < NI; ++ni)
                acc[mi][ni] = mfma16(bf_[ni], af[mi], acc[mi][ni]);   // swapped
        __syncthreads();
    }

    // ---- softmax epilogue ----
    const int base_rloc = wr * 64 + frow;        // + mi*16
    const float scale = 1.0f / 32.0f;

    // pass 1: mask + scale + row max (fg-reduce via shfl, wc-reduce via LDS)
#pragma unroll
    for (int mi = 0; mi < 4; ++mi) {
        const int rl = base_rloc + mi * 16;
        const int grow = qb * 128 + rl;
        float m = -3.0e38f;
#pragma unroll
        for (int ni = 0; ni < NI; ++ni)
#pragma unroll
            for (int r = 0; r < 4; ++r) {
                const int col = wc * Nw + ni * 16 + fg * 4 + r;
                float v = acc[mi][ni][r] * scale;
                if (col > grow) v = -3.0e38f;
                acc[mi][ni][r] = v;
                m = fmaxf(m, v);
            }
        m = fmaxf(m, __shfl_xor(m, 16));
        m = fmaxf(m, __shfl_xor(m, 32));
        if (fg == 0) red[rl * 4 + wc] = m;
    }
    __syncthreads();
    float mx[4];
#pragma unroll
    for (int mi = 0; mi < 4; ++mi) {
        const int rl = base_rloc + mi * 16;
        mx[mi] = fmaxf(fmaxf(red[rl * 4 + 0], red[rl * 4 + 1]),
                       fmaxf(red[rl * 4 + 2], red[rl * 4 + 3]));
    }
    __syncthreads();

    // pass 2: exp + row sum
#pragma unroll
    for (int mi = 0; mi < 4; ++mi) {
        const int rl = base_rloc + mi * 16;
        float s = 0.f;
#pragma unroll
        for (int ni = 0; ni < NI; ++ni)
#pragma unroll
            for (int r = 0; r < 4; ++r) {
                const float e = __expf(acc[mi][ni][r] - mx[mi]);   // masked -> exp(-inf)=0
                acc[mi][ni][r] = e;
                s += e;
            }
        s += __shfl_xor(s, 16);
        s += __shfl_xor(s, 32);
        if (fg == 0) red[rl * 4 + wc] = s;
    }
    __syncthreads();

    // pass 3: normalize + packed bf16 store
#pragma unroll
    for (int mi = 0; mi < 4; ++mi) {
        const int rl = base_rloc + mi * 16;
        const float inv = 1.0f / (red[rl * 4 + 0] + red[rl * 4 + 1] +
                                  red[rl * 4 + 2] + red[rl * 4 + 3]);
        const int grow = qb * 128 + rl;
#pragma unroll
        for (int ni = 0; ni < NI; ++ni) {
            bf16x4 o;
#pragma unroll
            for (int r = 0; r < 4; ++r) o[r] = (bf16_t)(acc[mi][ni][r] * inv);
            *(bf16x4*)&Pseg[(size_t)grow * 256 + wc * Nw + ni * 16 + fg * 4] = o;
        }
    }
}

// ---------- merged: fused QK^T+softmax (blocks 0..63) + V transpose (rest) ----------
// qk: bid = seg*2 + qb. qb0: rows 0-127 x cols 0-127 (tri); qb1: rows 128-255 x cols 0-255.
// P cols 128..255 of rows 0..127 never written (PV tri-skip never reads them).
// transpose: id2 = bid-64: seg=id2>>6, eb=(id2&63)>>2, kb=id2&3; 64x64 tile, 512 thr.
__global__ __launch_bounds__(512)
void qk_sm_tr_kernel(const bf16_t* __restrict__ qkv, bf16_t* __restrict__ P,
                     bf16_t* __restrict__ Vt)
{
    __shared__ __align__(16) char smem[26624];
    const int bid = blockIdx.x;
    const int tid = threadIdx.x;

    if (bid < 64) {
        const int seg = bid >> 1, qb = bid & 1;
        const bf16_t* Ab = qkv + (size_t)seg * 786432 + (size_t)qb * 128 * 3072; // Q rows
        const bf16_t* Bb = qkv + (size_t)seg * 786432 + 1024;                    // K rows
        bf16_t* Pseg = P + (size_t)seg * 65536;
        if (qb) qk_block<4>(Ab, Bb, Pseg, 1, smem, tid);
        else    qk_block<2>(Ab, Bb, Pseg, 0, smem, tid);
    } else {
        const int id2 = bid - 64;
        const int seg = id2 >> 6;
        const int rem = id2 & 63;
        const int eb = rem >> 2, kb = rem & 3;
        bf16_t* tile = (bf16_t*)smem;   // [64][65]
        const int rr = tid >> 3, cs = (tid & 7) * 8;
        const bf16_t* src = qkv + ((size_t)seg * 256 + kb * 64 + rr) * 3072
                                + 2048 + eb * 64 + cs;
        bf16x8 v = *(const bf16x8*)src;
#pragma unroll
        for (int i = 0; i < 8; ++i) tile[rr * 65 + cs + i] = v[i];
        __syncthreads();
        bf16x8 o;
#pragma unroll
        for (int i = 0; i < 8; ++i) o[i] = tile[(cs + i) * 65 + rr];
        *(bf16x8*)&Vt[(size_t)seg * 262144 + (size_t)(eb * 64 + rr) * 256 + kb * 64 + cs] = o;
    }
}

// ---------- LayerNorm (in place, bf16x8, 2 rows per block) ----------
__global__ __launch_bounds__(256)
void ln_kernel(bf16_t* __restrict__ qkv,
               const float* __restrict__ gamma, const float* __restrict__ beta)
{
    const int t = threadIdx.x;
    const int r = t >> 7;
    const int row = blockIdx.x * 2 + r;
    const int which = blockIdx.y;
    bf16_t* p = qkv + (size_t)row * 3072 + which * 1024;
    const int li = t & 127;
    const int c0 = li * 8;

    bf16x8 v = *(const bf16x8*)&p[c0];
    float f[8];
    float s = 0.f, ss = 0.f;
#pragma unroll
    for (int i = 0; i < 8; ++i) { f[i] = (float)v[i]; s += f[i]; ss += f[i] * f[i]; }
#pragma unroll
    for (int o = 32; o; o >>= 1) { s += __shfl_xor(s, o); ss += __shfl_xor(ss, o); }

    __shared__ float rs_[4], rss_[4];
    const int wave = t >> 6, lane = t & 63;
    if (lane == 0) { rs_[wave] = s; rss_[wave] = ss; }
    __syncthreads();
    s  = rs_[2 * r] + rs_[2 * r + 1];
    ss = rss_[2 * r] + rss_[2 * r + 1];

    const float mu   = s * (1.f / 1024.f);
    const float var  = ss * (1.f / 1024.f) - mu * mu;
    const float rstd = rsqrtf(var + 1e-5f);

    bf16x8 o;
#pragma unroll
    for (int i = 0; i < 8; ++i)
        o[i] = (bf16_t)((f[i] - mu) * rstd * gamma[c0 + i] + beta[c0 + i]);
    *(bf16x8*)&p[c0] = o;
}

// ---------- launch ----------

extern "C" void kernel_launch(void* const* d_in, const int* in_sizes, int n_in,
                              void* d_out, int out_size, void* d_ws, size_t ws_size,
                              hipStream_t stream)
{
    const float* x     = (const float*)d_in[0];
    const float* Wq    = (const float*)d_in[1];
    const float* Wk    = (const float*)d_in[2];
    const float* Wv    = (const float*)d_in[3];
    const float* Wo    = (const float*)d_in[4];
    const float* gamma = (const float*)d_in[5];
    const float* beta  = (const float*)d_in[6];
    float* out = (float*)d_out;

    char* ws = (char*)d_ws;
    bf16_t* Xe   = (bf16_t*)(ws);                  // 8192x1024 bf16   (16 MB)
    bf16_t* Wqkv = (bf16_t*)(ws + (16u  << 20));   // 3072x1024 bf16   ( 6 MB)
    bf16_t* Wob  = (bf16_t*)(ws + (22u  << 20));   // 1024x1024 bf16   ( 2 MB)
    bf16_t* QKV  = (bf16_t*)(ws + (24u  << 20));   // 8192x3072 bf16   (48 MB)
    bf16_t* P    = (bf16_t*)(ws + (80u  << 20));   // 32x256x256 bf16  ( 4 MB)
    bf16_t* Vt   = (bf16_t*)(ws + (84u  << 20));   // 32x1024x256 bf16 (16 MB)
    bf16_t* Y    = (bf16_t*)(ws + (100u << 20));   // 8192x1024 bf16   (16 MB)

    // prep: weight casts + dilated gather (one launch)
    prep_kernel<<<12288, 256, 0, stream>>>(Wq, Wk, Wv, Wo, x, Wqkv, Wob, Xe);

    // QKV projection: persistent 2-phase, 3 sub-tiles/block, 256 blocks, XCD-chunked
    gemm_mt<0, 3><<<dim3(8, 32), 512, 0, stream>>>(
        Xe, Wqkv, QKV, 1024, 1024, 3072);

    // LayerNorm q,k,v in place
    ln_kernel<<<dim3(4096, 3), 256, 0, stream>>>(QKV, gamma, beta);

    // fused: S = QK^T -> causal softmax -> P (direct), plus V transpose
    qk_sm_tr_kernel<<<64 + 2048, 512, 0, stream>>>(QKV, P, Vt);

    // Y = P V per segment (tri: bm==0 blocks only need K=128)
    gemm_nt<0><<<dim3(8, 2, 32), 256, 0, stream>>>(
        P, Vt, Y, 256, 256, 256, 1024,
        65536L, 262144L, 262144L, 1);

    // out = Y Wo^T scattered to even rows of d_out, odd rows zeroed
    gemm_mt<2, 1><<<dim3(8, 32), 512, 0, stream>>>(
        Y, Wob, out, 1024, 1024, 1024);
}